// Round 16
// baseline (1343.114 us; speedup 1.0000x reference)
//
#include <hip/hip_runtime.h>
#include <hip/hip_bf16.h>
#include <cmath>

// ---------------------------------------------------------------------------
// MoE "pure field": gate(softmax@T=e, top-5/8, renorm, sign) + dense 2-layer
// FFN over all experts, accumulated with signed gate weights.
//   N=8192, D_IN=1024, D_HID=4096, D_OUT=1024, E=8, k=5
// Round 19: R15 base (session best 1323us) + ONE fix: EPI=1 epilogue was
//   128 scalar 2B f16 stores/thread -> 32B wave fragments -> 2x HBM write
//   amplification (measured WRITE 262MB vs 128MB data; dispatch is
//   traffic-bound: 471MB @ 1.38TB/s = its full 341us). Now an f16
//   LDS-bounce (mirror of the proven EPI=2 bounce): wave-private 16KB
//   scratch, XOR-chunk swizzle (rowl>>2)&7, read back f16x8 -> 16B/lane
//   stores, 8 full 128B row segments per instruction. All else identical.
// ---------------------------------------------------------------------------

typedef _Float16 f16;
typedef _Float16 f16x8 __attribute__((ext_vector_type(8)));
typedef _Float16 f16x4 __attribute__((ext_vector_type(4)));
typedef float f32x4 __attribute__((ext_vector_type(4)));

#define NROWS 8192
#define DIN   1024
#define DHID  4096
#define DOUT  1024
#define NEXP  8

// workspace layout (bytes)
#define OFF_SGATE 0u
#define OFF_XH    262144u          // xh: 8192x1024 f16 = 16MB
#define OFF_W1T   17039360u        // w1t: 8x4096x1024 f16 = 64MB
#define OFF_W2T   84148224u        // w2t: 8x1024x4096 f16 = 64MB
#define OFF_P1    151257088u       // P1 partial f32 = 32MB
#define OFF_HH    184811520u       // hh group buffer: NE x 64MB
#define NEED_NE2  319029248ull
#define NEED_NE4  453246976ull

__device__ __forceinline__ void gload_lds16(const void* gsrc, void* ldsdst) {
  __builtin_amdgcn_global_load_lds(
      (const __attribute__((address_space(1))) unsigned int*)gsrc,
      (__attribute__((address_space(3))) unsigned int*)ldsdst, 16, 0, 0);
}

// ---------------------------------------------------------------------------
// Gate (proven form).
// ---------------------------------------------------------------------------
__global__ void gate_kernel(const float* __restrict__ x,
                            const float* __restrict__ gw,
                            const float* __restrict__ gb,
                            float* __restrict__ sgate) {
  const int row = blockIdx.x * 4 + (threadIdx.x >> 6);
  const int l = threadIdx.x & 63;
  const float* xr = x + (size_t)row * DIN;
  float acc[8] = {0.f,0.f,0.f,0.f,0.f,0.f,0.f,0.f};
#pragma unroll
  for (int j = 0; j < 16; ++j) {
    const int k = l + 64 * j;
    const float xv = xr[k];
    const float4 g0 = *(const float4*)(gw + (size_t)k * 8);
    const float4 g1 = *(const float4*)(gw + (size_t)k * 8 + 4);
    acc[0] += xv * g0.x; acc[1] += xv * g0.y; acc[2] += xv * g0.z; acc[3] += xv * g0.w;
    acc[4] += xv * g1.x; acc[5] += xv * g1.y; acc[6] += xv * g1.z; acc[7] += xv * g1.w;
  }
#pragma unroll
  for (int off = 32; off > 0; off >>= 1) {
#pragma unroll
    for (int e = 0; e < 8; ++e) acc[e] += __shfl_xor(acc[e], off, 64);
  }
  if (l == 0) {
    const float invT = 0.36787944117144233f;
    float p[8]; float mx = -1e30f;
#pragma unroll
    for (int e = 0; e < 8; ++e) { p[e] = (acc[e] + gb[e]) * invT; mx = fmaxf(mx, p[e]); }
    float S = 0.f;
#pragma unroll
    for (int e = 0; e < 8; ++e) { p[e] = expf(p[e] - mx); S += p[e]; }
    const float inv = 1.0f / S;
#pragma unroll
    for (int e = 0; e < 8; ++e) p[e] *= inv;
    bool keep[8] = {true,true,true,true,true,true,true,true};
    for (int t = 0; t < 3; ++t) {
      float pmin = 1e30f; int mi = -1;
      for (int e = 0; e < 8; ++e)
        if (keep[e] && (p[e] < pmin || (p[e] == pmin && e > mi))) { pmin = p[e]; mi = e; }
      keep[mi] = false;
    }
    float wsum = 0.f;
#pragma unroll
    for (int e = 0; e < 8; ++e) if (keep[e]) wsum += p[e];
    const float rinv = 1.0f / (wsum + 1e-8f);
#pragma unroll
    for (int e = 0; e < 8; ++e) {
      const float wv = keep[e] ? p[e] * rinv : 0.0f;
      sgate[(size_t)row * 8 + e] = (e < 4) ? wv : -wv;
    }
  }
}

__global__ void cvt_x_kernel(const float* __restrict__ x, f16* __restrict__ xh) {
  const size_t i = ((size_t)blockIdx.x * blockDim.x + threadIdx.x) * 4;
  const float4 v = *(const float4*)(x + i);
  f16x4 o = { (f16)v.x, (f16)v.y, (f16)v.z, (f16)v.w };
  *(f16x4*)(xh + i) = o;
}

// in f32 [E][R][C] -> out fp16 [E][C][R]
__global__ void transpose_cvt(const float* __restrict__ in, f16* __restrict__ out,
                              int R, int C) {
  __shared__ float tile[32][33];
  const int e = blockIdx.z;
  const float* ine = in + (size_t)e * R * C;
  f16* oute = out + (size_t)e * R * C;
  const int c0 = blockIdx.x * 32, r0 = blockIdx.y * 32;
  const int tx = threadIdx.x, ty = threadIdx.y;
#pragma unroll
  for (int i = 0; i < 4; ++i)
    tile[ty + i * 8][tx] = ine[(size_t)(r0 + ty + i * 8) * C + c0 + tx];
  __syncthreads();
#pragma unroll
  for (int i = 0; i < 4; ++i)
    oute[(size_t)(c0 + ty + i * 8) * R + r0 + tx] = (f16)tile[tx][ty + i * 8];
}

#define MFMAOP(a_, b_, c_) __builtin_amdgcn_mfma_f32_16x16x32_f16(a_, b_, c_, 0, 0, 0)

// ---------------------------------------------------------------------------
// gemm8p: 256x256 BK=64, 4 phases/tile, 4 half-tile LDS slots per operand
//   (R13-proven schedule/ledger/swizzle, unchanged).
//     p0: rd A f0-3 ks0+ks1 (8) + B g0-1 ks0+ks1 (4) | STG_B(T+1,h1) |
//         bar+lgkm0 | MFMA f0-3 x g0-1 x both ks (16)
//     p1: rd B g2-3 ks0+ks1 (4) | bar+lgkm0 | MFMA f0-3 x g2-3 (16)
//     p2: rd A f4-7 ks0+ks1 (8) | STG_B(T+2,h0) | bar+lgkm0 | MFMA f4-7xg0-1
//     p3: STG_A(T+2,h0+h1); VM6 [tail VM0] | bar+lgkm0 | MFMA f4-7 x g2-3
//   B-frags live all 4 phases; vmcnt(6) once/tile; 128B-row swizzle.
// EPI=1 (R15 n-partitioned merged decode): grid = NE*512; gx = XCDs per
//   expert (8/NE); per-XCD B-set 16/gx n-tiles (NE=4: 4MB = L2-resident).
//   Epilogue (R19): f16 LDS-bounce -> f16x8 stores (full-line writes).
// EPI=2: m-partitioned XCD decode (grid 256): XCD xx owns 8 m-tiles x all
//   4 n-tiles of K-half kh=xx>>2 (A-panel fetched once per XCD).
//   Segmented-B K-walk: bofs(tk)=(tk>>6)*DOUT*DHID+(tk&63)*64.
//   Aeff=A+kh*khA, Beff=B+kh*khB, P=kh?P1:P0.
//   Epilogue: per-wave LDS bounce -> float4 RMW (p1w -> plain write).
// ---------------------------------------------------------------------------
template <int EPI>
__global__ __launch_bounds__(512, 2) void gemm8p(
    const f16* __restrict__ A, int lda,
    const f16* __restrict__ B, int ldb, int nt,
    long long khA, long long khB,
    const float* __restrict__ bias,
    f16* __restrict__ outH, int ldc,
    float* outP0, float* outP1, int p1w,
    const float* __restrict__ sgate, int ebase, int gx) {
  __shared__ alignas(16) f16 lA[4 * 8192];   // 4 half-tile slots x 16KB
  __shared__ alignas(16) f16 lB[4 * 8192];
  const int tid = threadIdx.x;
  const int l = tid & 63, w = tid >> 6;
  const int wr = w >> 2, wc = w & 3;

  // T1 XCD swizzle (grid % 8 == 0 in all launches)
  const int nwg = gridDim.x, cpx = nwg >> 3;
  const int lg = ((int)blockIdx.x & 7) * cpx + ((int)blockIdx.x >> 3);

  int m0, n0, ei = 0;
  const f16* Aeff = A;
  const f16* Beff = B;
  float* P = nullptr;
  bool pw = false;
  if constexpr (EPI == 1) {
    // n-partitioned XCD decode: gx = XCDs per expert; each XCD owns
    // ntpx = 16/gx n-tiles x all 32 m-tiles of its expert.
    ei = lg >> 9;                       // 512 blocks per expert
    const int local = lg & 511;
    const int bpx = 512 / gx;           // blocks per XCD slice
    const int sub = local / bpx;        // XCD index within expert
    const int c = local % bpx;
    const int ntpx = 16 / gx;           // n-tiles per XCD
    m0 = (c / ntpx) * 256;              // 32 m-tiles
    n0 = (sub * ntpx + c % ntpx) * 256;
    Beff = B + (size_t)ei * DHID * DIN; // w1t expert panel
  } else {
    // m-partitioned XCD decode (grid 256): xx = XCD id in [0,8).
    const int xx = lg >> 5, cc = lg & 31;
    const int kh = xx >> 2;
    n0 = (cc & 3) * 256;
    m0 = (((xx & 3) << 3) + (cc >> 2)) * 256;
    Aeff = A + (size_t)kh * (size_t)khA;
    Beff = B + (size_t)kh * (size_t)khB;
    P = kh ? outP1 : outP0;
    pw = (p1w != 0);
  }

  // staging: thread -> (row tid>>3, chunk tid&7); source chunk pre-swizzled
  const int srow = tid >> 3;
  const int sxc = (tid & 7) ^ (srow & 7);
  const f16* pA = Aeff + (size_t)(m0 + srow) * lda + sxc * 8;
  const f16* pB = Beff + (size_t)(n0 + srow) * ldb + sxc * 8;
  f16* const dA = lA + w * 512;   // wave-uniform LDS base (+ lane*16B by HW)
  f16* const dB = lB + w * 512;

  // B K-walk offset (elements): segmented over folded experts (EPI=2)
  auto BOFS = [&](int tk) -> size_t {
    if constexpr (EPI == 1) return (size_t)tk * 64;
    else return (size_t)(tk >> 6) * (size_t)(DOUT * DHID) +
                (size_t)(tk & 63) * 64;
  };

#define STG_A(slot, h, tk) do { \
    const f16* s_ = pA + (size_t)(h) * 128 * lda + (size_t)(tk) * 64; \
    gload_lds16(s_,            dA + (slot) * 8192); \
    gload_lds16(s_ + 64 * lda, dA + (slot) * 8192 + 4096); \
  } while (0)
#define STG_B(slot, h, tk) do { \
    const f16* s_ = pB + (size_t)(h) * 128 * ldb + BOFS(tk); \
    gload_lds16(s_,            dB + (slot) * 8192); \
    gload_lds16(s_ + 64 * ldb, dB + (slot) * 8192 + 4096); \
  } while (0)

  // ds_read fragment offsets (bytes), same xor involution as the source
  const int cg = l >> 4, xr = l & 7;
  const int ok0 = ((cg ^ xr) << 4);
  const int ok1 = (((4 + cg) ^ xr) << 4);
  const char* const baA = (const char*)lA + (l & 15) * 128;
  const char* const baB = (const char*)lB + (wc & 1) * 8192 + (l & 15) * 128;

#define RDA(CA, f, o) (*(const f16x8*)(baA + ((CA) + wr) * 16384 + (f) * 2048 + (o)))
#define RDB(CB, g, o) (*(const f16x8*)(baB + ((CB) + (wc >> 1)) * 16384 + (g) * 2048 + (o)))
#define SYNC() do { __builtin_amdgcn_s_barrier(); \
    asm volatile("s_waitcnt lgkmcnt(0)" ::: "memory"); \
    __builtin_amdgcn_sched_barrier(0); } while (0)
#define ENDPH() do { __builtin_amdgcn_s_setprio(0); \
    __builtin_amdgcn_s_barrier(); } while (0)
#define VM6() do { asm volatile("s_waitcnt vmcnt(6)" ::: "memory"); \
    __builtin_amdgcn_sched_barrier(0); } while (0)
#define VM0() do { asm volatile("s_waitcnt vmcnt(0)" ::: "memory"); \
    __builtin_amdgcn_sched_barrier(0); } while (0)
#define MM(f, g, ar, br) acc[f][g] = MFMAOP(ar, br, acc[f][g])

  f32x4 acc[8][4] = {};
  f16x8 aA0,aA1,aB0,aB1,aC0,aC1,aD0,aD1;   // 4 m-frags x 2 kslices (reused)
  f16x8 b00,b01,b10,b11,b20,b21,b30,b31;   // 4 n-frags x 2 kslices

#define TILEBODY(T, CA, CB, SB1, SB0n, SA0n, SA1n) do { \
    /* phase 0: f0-3 both ks + g0-1 both ks (12 reads) */ \
    aA0 = RDA(CA, 0, ok0); aA1 = RDA(CA, 0, ok1); \
    aB0 = RDA(CA, 1, ok0); aB1 = RDA(CA, 1, ok1); \
    aC0 = RDA(CA, 2, ok0); aC1 = RDA(CA, 2, ok1); \
    aD0 = RDA(CA, 3, ok0); aD1 = RDA(CA, 3, ok1); \
    b00 = RDB(CB, 0, ok0); b01 = RDB(CB, 0, ok1); \
    b10 = RDB(CB, 1, ok0); b11 = RDB(CB, 1, ok1); \
    if ((T) + 1 < nt) STG_B(SB1, 1, (T) + 1); \
    SYNC(); \
    __builtin_amdgcn_s_setprio(1); \
    MM(0,0,aA0,b00); MM(0,1,aA0,b10); MM(1,0,aB0,b00); MM(1,1,aB0,b10); \
    MM(2,0,aC0,b00); MM(2,1,aC0,b10); MM(3,0,aD0,b00); MM(3,1,aD0,b10); \
    MM(0,0,aA1,b01); MM(0,1,aA1,b11); MM(1,0,aB1,b01); MM(1,1,aB1,b11); \
    MM(2,0,aC1,b01); MM(2,1,aC1,b11); MM(3,0,aD1,b01); MM(3,1,aD1,b11); \
    ENDPH(); \
    /* phase 1: g2-3 both ks (4 reads) */ \
    b20 = RDB(CB, 2, ok0); b21 = RDB(CB, 2, ok1); \
    b30 = RDB(CB, 3, ok0); b31 = RDB(CB, 3, ok1); \
    SYNC(); \
    __builtin_amdgcn_s_setprio(1); \
    MM(0,2,aA0,b20); MM(0,3,aA0,b30); MM(1,2,aB0,b20); MM(1,3,aB0,b30); \
    MM(2,2,aC0,b20); MM(2,3,aC0,b30); MM(3,2,aD0,b20); MM(3,3,aD0,b30); \
    MM(0,2,aA1,b21); MM(0,3,aA1,b31); MM(1,2,aB1,b21); MM(1,3,aB1,b31); \
    MM(2,2,aC1,b21); MM(2,3,aC1,b31); MM(3,2,aD1,b21); MM(3,3,aD1,b31); \
    ENDPH(); \
    /* phase 2: f4-7 both ks (8 reads) */ \
    aA0 = RDA(CA, 4, ok0); aA1 = RDA(CA, 4, ok1); \
    aB0 = RDA(CA, 5, ok0); aB1 = RDA(CA, 5, ok1); \
    aC0 = RDA(CA, 6, ok0); aC1 = RDA(CA, 6, ok1); \
    aD0 = RDA(CA, 7, ok0); aD1 = RDA(CA, 7, ok1); \
    if ((T) + 2 < nt) STG_B(SB0n, 0, (T) + 2); \
    SYNC(); \
    __builtin_amdgcn_s_setprio(1); \
    MM(4,0,aA0,b00); MM(4,1,aA0,b10); MM(5,0,aB0,b00); MM(5,1,aB0,b10); \
    MM(6,0,aC0,b00); MM(6,1,aC0,b10); MM(7,0,aD0,b00); MM(7,1,aD0,b10); \
    MM(4,0,aA1,b01); MM(4,1,aA1,b11); MM(5,0,aB1,b01); MM(5,1,aB1,b11); \
    MM(6,0,aC1,b01); MM(6,1,aC1,b11); MM(7,0,aD1,b01); MM(7,1,aD1,b11); \
    ENDPH(); \
    /* phase 3: stage A(T+2); counted vmcnt (tail VM0) */ \
    if ((T) + 2 < nt) { STG_A(SA0n, 0, (T) + 2); STG_A(SA1n, 1, (T) + 2); \
                        VM6(); } \
    else { VM0(); } \
    SYNC(); \
    __builtin_amdgcn_s_setprio(1); \
    MM(4,2,aA0,b20); MM(4,3,aA0,b30); MM(5,2,aB0,b20); MM(5,3,aB0,b30); \
    MM(6,2,aC0,b20); MM(6,3,aC0,b30); MM(7,2,aD0,b20); MM(7,3,aD0,b30); \
    MM(4,2,aA1,b21); MM(4,3,aA1,b31); MM(5,2,aB1,b21); MM(5,3,aB1,b31); \
    MM(6,2,aC1,b21); MM(6,3,aC1,b31); MM(7,2,aD1,b21); MM(7,3,aD1,b31); \
    ENDPH(); \
  } while (0)

  // prologue: tile0 (A0,B0,A1,B1) + tile1 (A0,B0,A1); 14 loads, drain to 6
  STG_A(0, 0, 0); STG_B(0, 0, 0); STG_A(1, 1, 0); STG_B(1, 1, 0);
  STG_A(2, 0, 1); STG_B(2, 0, 1); STG_A(3, 1, 1);
  asm volatile("s_waitcnt vmcnt(6)" ::: "memory");
  __builtin_amdgcn_s_barrier();

  for (int t = 0; t < nt; t += 2) {
    TILEBODY(t,     0, 0, 3, 0, 0, 1);
    TILEBODY(t + 1, 2, 2, 1, 2, 2, 3);
  }
  asm volatile("s_waitcnt vmcnt(0)" ::: "memory");

  // epilogue
  if constexpr (EPI == 1) {
    // f16 LDS-bounce epilogue (R19): assemble the wave's 128x64 output in
    // wave-private 16KB scratch, then f16x8 (16B/lane) stores: each
    // instruction writes 8 full 128B row segments (was: 128 scalar 2B
    // stores/thread -> 32B fragments -> 2x HBM write amplification).
    // XOR chunk swizzle xs=(rowl>>2)&7 keeps both passes <=2 lanes/bank.
    // Safe: all K-loop ds_reads drained (SYNC lgkm0 + final barrier);
    // scratch is wave-private; DS pipe in-order per wave (EPI=2-proven).
    f16* const scr = (w < 4) ? (f16*)lA + w * 8192
                             : (f16*)lB + (w - 4) * 8192;
    const int hl = l >> 4, ll = l & 15;
#pragma unroll
    for (int mi = 0; mi < 8; ++mi)
#pragma unroll
      for (int r = 0; r < 4; ++r) {
        const int rowl = mi * 16 + hl * 4 + r;
        const int xs = (rowl >> 2) & 7;
        const int row = m0 + wr * 128 + rowl;
        const float sg = sgate[(size_t)row * 8 + ebase + ei];
#pragma unroll
        for (int ni = 0; ni < 4; ++ni) {
          const int col = n0 + wc * 64 + ni * 16 + ll;
          const float v = acc[mi][ni][r] + bias[(size_t)ei * DHID + col];
          const int ch = (ni * 2 + (ll >> 3)) ^ xs;
          scr[rowl * 64 + ch * 8 + (ll & 7)] = (f16)(fmaxf(v, 0.0f) * sg);
        }
      }
    const int r8 = l >> 3, cc8 = l & 7;
#pragma unroll
    for (int i = 0; i < 16; ++i) {
      const int rowl = r8 + i * 8;
      const int xs = (rowl >> 2) & 7;
      const f16x8 v = *(const f16x8*)(scr + rowl * 64 + ((cc8 ^ xs) << 3));
      const int row = m0 + wr * 128 + rowl;
      *(f16x8*)(outH + (size_t)row * ldc + (size_t)ei * DHID + n0 +
                wc * 64 + cc8 * 8) = v;
    }
  } else {
    // float4 LDS-bounce RMW epilogue; LDS free after final ENDPH barrier.
    // Wave-private scratch, in-order DS pipe -> no barriers needed.
    float* const scr = (w < 4) ? (float*)lA + w * 4096
                               : (float*)lB + (w - 4) * 4096;
    const int hl = l >> 4, ll = l & 15;
#pragma unroll
    for (int p = 0; p < 2; ++p) {
#pragma unroll
      for (int mi4 = 0; mi4 < 4; ++mi4)
#pragma unroll
        for (int r = 0; r < 4; ++r) {
          const int rowl = mi4 * 16 + hl * 4 + r;
#pragma unroll
          for (int ni = 0; ni < 4; ++ni)
            scr[rowl * 64 + ni * 16 + ll] = acc[p * 4 + mi4][ni][r];
        }
#pragma unroll
      for (int i = 0; i < 16; ++i) {
        const int rowl = hl + i * 4;
        f32x4 v = *(const f32x4*)(scr + rowl * 64 + ll * 4);
        const int row = m0 + wr * 128 + p * 64 + rowl;
        const int col = n0 + wc * 64 + ll * 4;
        f32x4* gp = (f32x4*)(P + (size_t)row * 1024 + col);
        if (!pw) {
          const f32x4 g = *gp;
          v[0] += g[0]; v[1] += g[1]; v[2] += g[2]; v[3] += g[3];
        }
        *gp = v;
      }
    }
  }
#undef STG_A
#undef STG_B
#undef RDA
#undef RDB
#undef SYNC
#undef ENDPH
#undef VM6
#undef VM0
#undef MM
#undef TILEBODY
}

// out = [p0 + p1 +] sum_e sg[n,e]*b2[e,:]   (float4-vectorized)
// NOTE: p0 may alias out -> no __restrict__ on p0/out.
template <bool WITHP>
__global__ void finalize_out(const float* p0,
                             const float* __restrict__ p1,
                             const float* __restrict__ sgate,
                             const float* __restrict__ b2,
                             float* out) {
  const int i = blockIdx.x * 256 + threadIdx.x;   // float4 index, 2M total
  const int n = i >> 8, c4 = i & 255;
  float4 a = make_float4(0.f, 0.f, 0.f, 0.f);
  if constexpr (WITHP) {
    const float4 u = ((const float4*)p0)[i];
    const float4 v = ((const float4*)p1)[i];
    a.x = u.x + v.x; a.y = u.y + v.y; a.z = u.z + v.z; a.w = u.w + v.w;
  }
  const float* sg = sgate + (size_t)n * 8;
#pragma unroll
  for (int e = 0; e < 8; ++e) {
    const float s = sg[e];
    const float4 bv = ((const float4*)(b2 + (size_t)e * 1024))[c4];
    a.x += s * bv.x; a.y += s * bv.y; a.z += s * bv.z; a.w += s * bv.w;
  }
  ((float4*)out)[i] = a;
}

extern "C" void kernel_launch(void* const* d_in, const int* in_sizes, int n_in,
                              void* d_out, int out_size, void* d_ws, size_t ws_size,
                              hipStream_t stream) {
  const float* x  = (const float*)d_in[0];
  const float* gw = (const float*)d_in[1];
  const float* gb = (const float*)d_in[2];
  const float* w1 = (const float*)d_in[3];
  const float* b1 = (const float*)d_in[4];
  const float* w2 = (const float*)d_in[5];
  const float* b2 = (const float*)d_in[6];
  float* out = (float*)d_out;

  char* ws = (char*)d_ws;
  float* sgate = (float*)(ws + OFF_SGATE);
  f16* xh  = (f16*)(ws + OFF_XH);
  f16* w1t = (f16*)(ws + OFF_W1T);
  f16* w2t = (f16*)(ws + OFF_W2T);
  float* p1 = (float*)(ws + OFF_P1);
  f16* hh  = (f16*)(ws + OFF_HH);

  // expert-group fold width by ws tier (NE=4 fires; proven R13/R16).
  const int NE = (ws_size >= NEED_NE4) ? 4 :
                 (ws_size >= NEED_NE2) ? 2 : 1;
  const int ngrp = NEXP / NE;
  const int xpe = 8 / NE;   // XCDs per expert in the merged GEMM1

  gate_kernel<<<NROWS / 4, 256, 0, stream>>>(x, gw, gb, sgate);
  cvt_x_kernel<<<(NROWS * DIN) / (256 * 4), 256, 0, stream>>>(x, xh);
  transpose_cvt<<<dim3(DHID / 32, DIN / 32, NEXP), dim3(32, 8), 0, stream>>>(w1, w1t, DIN, DHID);
  transpose_cvt<<<dim3(DOUT / 32, DHID / 32, NEXP), dim3(32, 8), 0, stream>>>(w2, w2t, DHID, DOUT);

  const long long khA = (long long)NE * 2048;                  // A K-half cols
  const long long khB = (NE >= 2) ? (long long)(NE / 2) * DOUT * DHID
                                  : 2048LL;                    // within-expert
  const int nt2 = NE * 32;                                     // K-half / 64
  for (int g = 0; g < ngrp; ++g) {
    // merged GEMM1 (one launch per group; n-partitioned XCD decode)
    gemm8p<1><<<NE * 512, 512, 0, stream>>>(
        xh, DIN, w1t + (size_t)g * NE * DHID * DIN, DIN, DIN / 64,
        0, 0,
        b1 + (size_t)g * NE * DHID, hh, NE * DHID,
        nullptr, nullptr, 0, sgate, g * NE, xpe);
    gemm8p<2><<<256, 512, 0, stream>>>(
        hh, NE * DHID, w2t + (size_t)g * NE * DOUT * DHID, DHID, nt2,
        khA, khB,
        nullptr, nullptr, 0, out, p1, (g == 0) ? 1 : 0, nullptr, 0, 0);
  }
  finalize_out<true><<<(NROWS * DOUT) / (256 * 4), 256, 0, stream>>>(
      out, p1, sgate, b2, out);
}

// Round 17
// 1322.256 us; speedup vs baseline: 1.0158x; 1.0158x over previous
//
#include <hip/hip_runtime.h>
#include <hip/hip_bf16.h>
#include <cmath>

// ---------------------------------------------------------------------------
// MoE "pure field": gate(softmax@T=e, top-5/8, renorm, sign) + dense 2-layer
// FFN over all experts, accumulated with signed gate weights.
//   N=8192, D_IN=1024, D_HID=4096, D_OUT=1024, E=8, k=5
// Round 20 (final): revert to the R15 session-best configuration (1323us).
//   R16's f16-bounce epilogue was built on an arithmetic error (hh @ NE=4
//   is 256MiB, so WRITE 262MB was exact data, not 2x amplification); it
//   added 4.2M bank conflicts for zero gain -> reverted.
//   Final structure: merged GEMM1 (1 launch/group, n-partitioned XCD
//   decode, 4MB L2-resident B-panels) -> NE=4 GEMM2 (m-partitioned XCD
//   split-K, segmented-B, LDS-bounce float4 RMW epilogue), R13-proven
//   256x256 BK=64 4-phase vmcnt(6) loop throughout.
// ---------------------------------------------------------------------------

typedef _Float16 f16;
typedef _Float16 f16x8 __attribute__((ext_vector_type(8)));
typedef _Float16 f16x4 __attribute__((ext_vector_type(4)));
typedef float f32x4 __attribute__((ext_vector_type(4)));

#define NROWS 8192
#define DIN   1024
#define DHID  4096
#define DOUT  1024
#define NEXP  8

// workspace layout (bytes)
#define OFF_SGATE 0u
#define OFF_XH    262144u          // xh: 8192x1024 f16 = 16MB
#define OFF_W1T   17039360u        // w1t: 8x4096x1024 f16 = 64MB
#define OFF_W2T   84148224u        // w2t: 8x1024x4096 f16 = 64MB
#define OFF_P1    151257088u       // P1 partial f32 = 32MB
#define OFF_HH    184811520u       // hh group buffer: NE x 64MB
#define NEED_NE2  319029248ull
#define NEED_NE4  453246976ull

__device__ __forceinline__ void gload_lds16(const void* gsrc, void* ldsdst) {
  __builtin_amdgcn_global_load_lds(
      (const __attribute__((address_space(1))) unsigned int*)gsrc,
      (__attribute__((address_space(3))) unsigned int*)ldsdst, 16, 0, 0);
}

// ---------------------------------------------------------------------------
// Gate (proven form).
// ---------------------------------------------------------------------------
__global__ void gate_kernel(const float* __restrict__ x,
                            const float* __restrict__ gw,
                            const float* __restrict__ gb,
                            float* __restrict__ sgate) {
  const int row = blockIdx.x * 4 + (threadIdx.x >> 6);
  const int l = threadIdx.x & 63;
  const float* xr = x + (size_t)row * DIN;
  float acc[8] = {0.f,0.f,0.f,0.f,0.f,0.f,0.f,0.f};
#pragma unroll
  for (int j = 0; j < 16; ++j) {
    const int k = l + 64 * j;
    const float xv = xr[k];
    const float4 g0 = *(const float4*)(gw + (size_t)k * 8);
    const float4 g1 = *(const float4*)(gw + (size_t)k * 8 + 4);
    acc[0] += xv * g0.x; acc[1] += xv * g0.y; acc[2] += xv * g0.z; acc[3] += xv * g0.w;
    acc[4] += xv * g1.x; acc[5] += xv * g1.y; acc[6] += xv * g1.z; acc[7] += xv * g1.w;
  }
#pragma unroll
  for (int off = 32; off > 0; off >>= 1) {
#pragma unroll
    for (int e = 0; e < 8; ++e) acc[e] += __shfl_xor(acc[e], off, 64);
  }
  if (l == 0) {
    const float invT = 0.36787944117144233f;
    float p[8]; float mx = -1e30f;
#pragma unroll
    for (int e = 0; e < 8; ++e) { p[e] = (acc[e] + gb[e]) * invT; mx = fmaxf(mx, p[e]); }
    float S = 0.f;
#pragma unroll
    for (int e = 0; e < 8; ++e) { p[e] = expf(p[e] - mx); S += p[e]; }
    const float inv = 1.0f / S;
#pragma unroll
    for (int e = 0; e < 8; ++e) p[e] *= inv;
    bool keep[8] = {true,true,true,true,true,true,true,true};
    for (int t = 0; t < 3; ++t) {
      float pmin = 1e30f; int mi = -1;
      for (int e = 0; e < 8; ++e)
        if (keep[e] && (p[e] < pmin || (p[e] == pmin && e > mi))) { pmin = p[e]; mi = e; }
      keep[mi] = false;
    }
    float wsum = 0.f;
#pragma unroll
    for (int e = 0; e < 8; ++e) if (keep[e]) wsum += p[e];
    const float rinv = 1.0f / (wsum + 1e-8f);
#pragma unroll
    for (int e = 0; e < 8; ++e) {
      const float wv = keep[e] ? p[e] * rinv : 0.0f;
      sgate[(size_t)row * 8 + e] = (e < 4) ? wv : -wv;
    }
  }
}

__global__ void cvt_x_kernel(const float* __restrict__ x, f16* __restrict__ xh) {
  const size_t i = ((size_t)blockIdx.x * blockDim.x + threadIdx.x) * 4;
  const float4 v = *(const float4*)(x + i);
  f16x4 o = { (f16)v.x, (f16)v.y, (f16)v.z, (f16)v.w };
  *(f16x4*)(xh + i) = o;
}

// in f32 [E][R][C] -> out fp16 [E][C][R]
__global__ void transpose_cvt(const float* __restrict__ in, f16* __restrict__ out,
                              int R, int C) {
  __shared__ float tile[32][33];
  const int e = blockIdx.z;
  const float* ine = in + (size_t)e * R * C;
  f16* oute = out + (size_t)e * R * C;
  const int c0 = blockIdx.x * 32, r0 = blockIdx.y * 32;
  const int tx = threadIdx.x, ty = threadIdx.y;
#pragma unroll
  for (int i = 0; i < 4; ++i)
    tile[ty + i * 8][tx] = ine[(size_t)(r0 + ty + i * 8) * C + c0 + tx];
  __syncthreads();
#pragma unroll
  for (int i = 0; i < 4; ++i)
    oute[(size_t)(c0 + ty + i * 8) * R + r0 + tx] = (f16)tile[tx][ty + i * 8];
}

#define MFMAOP(a_, b_, c_) __builtin_amdgcn_mfma_f32_16x16x32_f16(a_, b_, c_, 0, 0, 0)

// ---------------------------------------------------------------------------
// gemm8p: 256x256 BK=64, 4 phases/tile, 4 half-tile LDS slots per operand
//   (R13-proven schedule/ledger/swizzle, unchanged).
//     p0: rd A f0-3 ks0+ks1 (8) + B g0-1 ks0+ks1 (4) | STG_B(T+1,h1) |
//         bar+lgkm0 | MFMA f0-3 x g0-1 x both ks (16)
//     p1: rd B g2-3 ks0+ks1 (4) | bar+lgkm0 | MFMA f0-3 x g2-3 (16)
//     p2: rd A f4-7 ks0+ks1 (8) | STG_B(T+2,h0) | bar+lgkm0 | MFMA f4-7xg0-1
//     p3: STG_A(T+2,h0+h1); VM6 [tail VM0] | bar+lgkm0 | MFMA f4-7 x g2-3
//   B-frags live all 4 phases; vmcnt(6) once/tile; 128B-row swizzle.
// EPI=1 (n-partitioned merged decode): grid = NE*512; gx = XCDs per
//   expert (8/NE); per-XCD B-set 16/gx n-tiles (NE=4: 4MB = L2-resident).
//   Epilogue: direct f16 stores (L2 coalesces to full lines; measured
//   WRITE == exact data size -- R16's bounce was a net loss, reverted).
// EPI=2: m-partitioned XCD decode (grid 256): XCD xx owns 8 m-tiles x all
//   4 n-tiles of K-half kh=xx>>2 (A-panel fetched once per XCD).
//   Segmented-B K-walk: bofs(tk)=(tk>>6)*DOUT*DHID+(tk&63)*64.
//   Aeff=A+kh*khA, Beff=B+kh*khB, P=kh?P1:P0.
//   Epilogue: per-wave LDS bounce -> float4 RMW (p1w -> plain write).
// ---------------------------------------------------------------------------
template <int EPI>
__global__ __launch_bounds__(512, 2) void gemm8p(
    const f16* __restrict__ A, int lda,
    const f16* __restrict__ B, int ldb, int nt,
    long long khA, long long khB,
    const float* __restrict__ bias,
    f16* __restrict__ outH, int ldc,
    float* outP0, float* outP1, int p1w,
    const float* __restrict__ sgate, int ebase, int gx) {
  __shared__ alignas(16) f16 lA[4 * 8192];   // 4 half-tile slots x 16KB
  __shared__ alignas(16) f16 lB[4 * 8192];
  const int tid = threadIdx.x;
  const int l = tid & 63, w = tid >> 6;
  const int wr = w >> 2, wc = w & 3;

  // T1 XCD swizzle (grid % 8 == 0 in all launches)
  const int nwg = gridDim.x, cpx = nwg >> 3;
  const int lg = ((int)blockIdx.x & 7) * cpx + ((int)blockIdx.x >> 3);

  int m0, n0, ei = 0;
  const f16* Aeff = A;
  const f16* Beff = B;
  float* P = nullptr;
  bool pw = false;
  if constexpr (EPI == 1) {
    // n-partitioned XCD decode: gx = XCDs per expert; each XCD owns
    // ntpx = 16/gx n-tiles x all 32 m-tiles of its expert.
    ei = lg >> 9;                       // 512 blocks per expert
    const int local = lg & 511;
    const int bpx = 512 / gx;           // blocks per XCD slice
    const int sub = local / bpx;        // XCD index within expert
    const int c = local % bpx;
    const int ntpx = 16 / gx;           // n-tiles per XCD
    m0 = (c / ntpx) * 256;              // 32 m-tiles
    n0 = (sub * ntpx + c % ntpx) * 256;
    Beff = B + (size_t)ei * DHID * DIN; // w1t expert panel
  } else {
    // m-partitioned XCD decode (grid 256): xx = XCD id in [0,8).
    const int xx = lg >> 5, cc = lg & 31;
    const int kh = xx >> 2;
    n0 = (cc & 3) * 256;
    m0 = (((xx & 3) << 3) + (cc >> 2)) * 256;
    Aeff = A + (size_t)kh * (size_t)khA;
    Beff = B + (size_t)kh * (size_t)khB;
    P = kh ? outP1 : outP0;
    pw = (p1w != 0);
  }

  // staging: thread -> (row tid>>3, chunk tid&7); source chunk pre-swizzled
  const int srow = tid >> 3;
  const int sxc = (tid & 7) ^ (srow & 7);
  const f16* pA = Aeff + (size_t)(m0 + srow) * lda + sxc * 8;
  const f16* pB = Beff + (size_t)(n0 + srow) * ldb + sxc * 8;
  f16* const dA = lA + w * 512;   // wave-uniform LDS base (+ lane*16B by HW)
  f16* const dB = lB + w * 512;

  // B K-walk offset (elements): segmented over folded experts (EPI=2)
  auto BOFS = [&](int tk) -> size_t {
    if constexpr (EPI == 1) return (size_t)tk * 64;
    else return (size_t)(tk >> 6) * (size_t)(DOUT * DHID) +
                (size_t)(tk & 63) * 64;
  };

#define STG_A(slot, h, tk) do { \
    const f16* s_ = pA + (size_t)(h) * 128 * lda + (size_t)(tk) * 64; \
    gload_lds16(s_,            dA + (slot) * 8192); \
    gload_lds16(s_ + 64 * lda, dA + (slot) * 8192 + 4096); \
  } while (0)
#define STG_B(slot, h, tk) do { \
    const f16* s_ = pB + (size_t)(h) * 128 * ldb + BOFS(tk); \
    gload_lds16(s_,            dB + (slot) * 8192); \
    gload_lds16(s_ + 64 * ldb, dB + (slot) * 8192 + 4096); \
  } while (0)

  // ds_read fragment offsets (bytes), same xor involution as the source
  const int cg = l >> 4, xr = l & 7;
  const int ok0 = ((cg ^ xr) << 4);
  const int ok1 = (((4 + cg) ^ xr) << 4);
  const char* const baA = (const char*)lA + (l & 15) * 128;
  const char* const baB = (const char*)lB + (wc & 1) * 8192 + (l & 15) * 128;

#define RDA(CA, f, o) (*(const f16x8*)(baA + ((CA) + wr) * 16384 + (f) * 2048 + (o)))
#define RDB(CB, g, o) (*(const f16x8*)(baB + ((CB) + (wc >> 1)) * 16384 + (g) * 2048 + (o)))
#define SYNC() do { __builtin_amdgcn_s_barrier(); \
    asm volatile("s_waitcnt lgkmcnt(0)" ::: "memory"); \
    __builtin_amdgcn_sched_barrier(0); } while (0)
#define ENDPH() do { __builtin_amdgcn_s_setprio(0); \
    __builtin_amdgcn_s_barrier(); } while (0)
#define VM6() do { asm volatile("s_waitcnt vmcnt(6)" ::: "memory"); \
    __builtin_amdgcn_sched_barrier(0); } while (0)
#define VM0() do { asm volatile("s_waitcnt vmcnt(0)" ::: "memory"); \
    __builtin_amdgcn_sched_barrier(0); } while (0)
#define MM(f, g, ar, br) acc[f][g] = MFMAOP(ar, br, acc[f][g])

  f32x4 acc[8][4] = {};
  f16x8 aA0,aA1,aB0,aB1,aC0,aC1,aD0,aD1;   // 4 m-frags x 2 kslices (reused)
  f16x8 b00,b01,b10,b11,b20,b21,b30,b31;   // 4 n-frags x 2 kslices

#define TILEBODY(T, CA, CB, SB1, SB0n, SA0n, SA1n) do { \
    /* phase 0: f0-3 both ks + g0-1 both ks (12 reads) */ \
    aA0 = RDA(CA, 0, ok0); aA1 = RDA(CA, 0, ok1); \
    aB0 = RDA(CA, 1, ok0); aB1 = RDA(CA, 1, ok1); \
    aC0 = RDA(CA, 2, ok0); aC1 = RDA(CA, 2, ok1); \
    aD0 = RDA(CA, 3, ok0); aD1 = RDA(CA, 3, ok1); \
    b00 = RDB(CB, 0, ok0); b01 = RDB(CB, 0, ok1); \
    b10 = RDB(CB, 1, ok0); b11 = RDB(CB, 1, ok1); \
    if ((T) + 1 < nt) STG_B(SB1, 1, (T) + 1); \
    SYNC(); \
    __builtin_amdgcn_s_setprio(1); \
    MM(0,0,aA0,b00); MM(0,1,aA0,b10); MM(1,0,aB0,b00); MM(1,1,aB0,b10); \
    MM(2,0,aC0,b00); MM(2,1,aC0,b10); MM(3,0,aD0,b00); MM(3,1,aD0,b10); \
    MM(0,0,aA1,b01); MM(0,1,aA1,b11); MM(1,0,aB1,b01); MM(1,1,aB1,b11); \
    MM(2,0,aC1,b01); MM(2,1,aC1,b11); MM(3,0,aD1,b01); MM(3,1,aD1,b11); \
    ENDPH(); \
    /* phase 1: g2-3 both ks (4 reads) */ \
    b20 = RDB(CB, 2, ok0); b21 = RDB(CB, 2, ok1); \
    b30 = RDB(CB, 3, ok0); b31 = RDB(CB, 3, ok1); \
    SYNC(); \
    __builtin_amdgcn_s_setprio(1); \
    MM(0,2,aA0,b20); MM(0,3,aA0,b30); MM(1,2,aB0,b20); MM(1,3,aB0,b30); \
    MM(2,2,aC0,b20); MM(2,3,aC0,b30); MM(3,2,aD0,b20); MM(3,3,aD0,b30); \
    MM(0,2,aA1,b21); MM(0,3,aA1,b31); MM(1,2,aB1,b21); MM(1,3,aB1,b31); \
    MM(2,2,aC1,b21); MM(2,3,aC1,b31); MM(3,2,aD1,b21); MM(3,3,aD1,b31); \
    ENDPH(); \
    /* phase 2: f4-7 both ks (8 reads) */ \
    aA0 = RDA(CA, 4, ok0); aA1 = RDA(CA, 4, ok1); \
    aB0 = RDA(CA, 5, ok0); aB1 = RDA(CA, 5, ok1); \
    aC0 = RDA(CA, 6, ok0); aC1 = RDA(CA, 6, ok1); \
    aD0 = RDA(CA, 7, ok0); aD1 = RDA(CA, 7, ok1); \
    if ((T) + 2 < nt) STG_B(SB0n, 0, (T) + 2); \
    SYNC(); \
    __builtin_amdgcn_s_setprio(1); \
    MM(4,0,aA0,b00); MM(4,1,aA0,b10); MM(5,0,aB0,b00); MM(5,1,aB0,b10); \
    MM(6,0,aC0,b00); MM(6,1,aC0,b10); MM(7,0,aD0,b00); MM(7,1,aD0,b10); \
    MM(4,0,aA1,b01); MM(4,1,aA1,b11); MM(5,0,aB1,b01); MM(5,1,aB1,b11); \
    MM(6,0,aC1,b01); MM(6,1,aC1,b11); MM(7,0,aD1,b01); MM(7,1,aD1,b11); \
    ENDPH(); \
    /* phase 3: stage A(T+2); counted vmcnt (tail VM0) */ \
    if ((T) + 2 < nt) { STG_A(SA0n, 0, (T) + 2); STG_A(SA1n, 1, (T) + 2); \
                        VM6(); } \
    else { VM0(); } \
    SYNC(); \
    __builtin_amdgcn_s_setprio(1); \
    MM(4,2,aA0,b20); MM(4,3,aA0,b30); MM(5,2,aB0,b20); MM(5,3,aB0,b30); \
    MM(6,2,aC0,b20); MM(6,3,aC0,b30); MM(7,2,aD0,b20); MM(7,3,aD0,b30); \
    MM(4,2,aA1,b21); MM(4,3,aA1,b31); MM(5,2,aB1,b21); MM(5,3,aB1,b31); \
    MM(6,2,aC1,b21); MM(6,3,aC1,b31); MM(7,2,aD1,b21); MM(7,3,aD1,b31); \
    ENDPH(); \
  } while (0)

  // prologue: tile0 (A0,B0,A1,B1) + tile1 (A0,B0,A1); 14 loads, drain to 6
  STG_A(0, 0, 0); STG_B(0, 0, 0); STG_A(1, 1, 0); STG_B(1, 1, 0);
  STG_A(2, 0, 1); STG_B(2, 0, 1); STG_A(3, 1, 1);
  asm volatile("s_waitcnt vmcnt(6)" ::: "memory");
  __builtin_amdgcn_s_barrier();

  for (int t = 0; t < nt; t += 2) {
    TILEBODY(t,     0, 0, 3, 0, 0, 1);
    TILEBODY(t + 1, 2, 2, 1, 2, 2, 3);
  }
  asm volatile("s_waitcnt vmcnt(0)" ::: "memory");

  // epilogue
  if constexpr (EPI == 1) {
#pragma unroll
    for (int mi = 0; mi < 8; ++mi)
#pragma unroll
      for (int r = 0; r < 4; ++r) {
        const int row = m0 + wr * 128 + mi * 16 + (l >> 4) * 4 + r;
        const float sg = sgate[(size_t)row * 8 + ebase + ei];
#pragma unroll
        for (int ni = 0; ni < 4; ++ni) {
          const int col = n0 + wc * 64 + ni * 16 + (l & 15);
          const float v = acc[mi][ni][r] + bias[(size_t)ei * DHID + col];
          outH[(size_t)row * ldc + (size_t)ei * DHID + col] =
              (f16)(fmaxf(v, 0.0f) * sg);
        }
      }
  } else {
    // float4 LDS-bounce RMW epilogue; LDS free after final ENDPH barrier.
    // Wave-private scratch, in-order DS pipe -> no barriers needed.
    float* const scr = (w < 4) ? (float*)lA + w * 4096
                               : (float*)lB + (w - 4) * 4096;
    const int hl = l >> 4, ll = l & 15;
#pragma unroll
    for (int p = 0; p < 2; ++p) {
#pragma unroll
      for (int mi4 = 0; mi4 < 4; ++mi4)
#pragma unroll
        for (int r = 0; r < 4; ++r) {
          const int rowl = mi4 * 16 + hl * 4 + r;
#pragma unroll
          for (int ni = 0; ni < 4; ++ni)
            scr[rowl * 64 + ni * 16 + ll] = acc[p * 4 + mi4][ni][r];
        }
#pragma unroll
      for (int i = 0; i < 16; ++i) {
        const int rowl = hl + i * 4;
        f32x4 v = *(const f32x4*)(scr + rowl * 64 + ll * 4);
        const int row = m0 + wr * 128 + p * 64 + rowl;
        const int col = n0 + wc * 64 + ll * 4;
        f32x4* gp = (f32x4*)(P + (size_t)row * 1024 + col);
        if (!pw) {
          const f32x4 g = *gp;
          v[0] += g[0]; v[1] += g[1]; v[2] += g[2]; v[3] += g[3];
        }
        *gp = v;
      }
    }
  }
#undef STG_A
#undef STG_B
#undef RDA
#undef RDB
#undef SYNC
#undef ENDPH
#undef VM6
#undef VM0
#undef MM
#undef TILEBODY
}

// out = [p0 + p1 +] sum_e sg[n,e]*b2[e,:]   (float4-vectorized)
// NOTE: p0 may alias out -> no __restrict__ on p0/out.
template <bool WITHP>
__global__ void finalize_out(const float* p0,
                             const float* __restrict__ p1,
                             const float* __restrict__ sgate,
                             const float* __restrict__ b2,
                             float* out) {
  const int i = blockIdx.x * 256 + threadIdx.x;   // float4 index, 2M total
  const int n = i >> 8, c4 = i & 255;
  float4 a = make_float4(0.f, 0.f, 0.f, 0.f);
  if constexpr (WITHP) {
    const float4 u = ((const float4*)p0)[i];
    const float4 v = ((const float4*)p1)[i];
    a.x = u.x + v.x; a.y = u.y + v.y; a.z = u.z + v.z; a.w = u.w + v.w;
  }
  const float* sg = sgate + (size_t)n * 8;
#pragma unroll
  for (int e = 0; e < 8; ++e) {
    const float s = sg[e];
    const float4 bv = ((const float4*)(b2 + (size_t)e * 1024))[c4];
    a.x += s * bv.x; a.y += s * bv.y; a.z += s * bv.z; a.w += s * bv.w;
  }
  ((float4*)out)[i] = a;
}

extern "C" void kernel_launch(void* const* d_in, const int* in_sizes, int n_in,
                              void* d_out, int out_size, void* d_ws, size_t ws_size,
                              hipStream_t stream) {
  const float* x  = (const float*)d_in[0];
  const float* gw = (const float*)d_in[1];
  const float* gb = (const float*)d_in[2];
  const float* w1 = (const float*)d_in[3];
  const float* b1 = (const float*)d_in[4];
  const float* w2 = (const float*)d_in[5];
  const float* b2 = (const float*)d_in[6];
  float* out = (float*)d_out;

  char* ws = (char*)d_ws;
  float* sgate = (float*)(ws + OFF_SGATE);
  f16* xh  = (f16*)(ws + OFF_XH);
  f16* w1t = (f16*)(ws + OFF_W1T);
  f16* w2t = (f16*)(ws + OFF_W2T);
  float* p1 = (float*)(ws + OFF_P1);
  f16* hh  = (f16*)(ws + OFF_HH);

  // expert-group fold width by ws tier (NE=4 fires; proven R13/R16).
  const int NE = (ws_size >= NEED_NE4) ? 4 :
                 (ws_size >= NEED_NE2) ? 2 : 1;
  const int ngrp = NEXP / NE;
  const int xpe = 8 / NE;   // XCDs per expert in the merged GEMM1

  gate_kernel<<<NROWS / 4, 256, 0, stream>>>(x, gw, gb, sgate);
  cvt_x_kernel<<<(NROWS * DIN) / (256 * 4), 256, 0, stream>>>(x, xh);
  transpose_cvt<<<dim3(DHID / 32, DIN / 32, NEXP), dim3(32, 8), 0, stream>>>(w1, w1t, DIN, DHID);
  transpose_cvt<<<dim3(DOUT / 32, DHID / 32, NEXP), dim3(32, 8), 0, stream>>>(w2, w2t, DHID, DOUT);

  const long long khA = (long long)NE * 2048;                  // A K-half cols
  const long long khB = (NE >= 2) ? (long long)(NE / 2) * DOUT * DHID
                                  : 2048LL;                    // within-expert
  const int nt2 = NE * 32;                                     // K-half / 64
  for (int g = 0; g < ngrp; ++g) {
    // merged GEMM1 (one launch per group; n-partitioned XCD decode)
    gemm8p<1><<<NE * 512, 512, 0, stream>>>(
        xh, DIN, w1t + (size_t)g * NE * DHID * DIN, DIN, DIN / 64,
        0, 0,
        b1 + (size_t)g * NE * DHID, hh, NE * DHID,
        nullptr, nullptr, 0, sgate, g * NE, xpe);
    gemm8p<2><<<256, 512, 0, stream>>>(
        hh, NE * DHID, w2t + (size_t)g * NE * DOUT * DHID, DHID, nt2,
        khA, khB,
        nullptr, nullptr, 0, out, p1, (g == 0) ? 1 : 0, nullptr, 0, 0);
  }
  finalize_out<true><<<(NROWS * DOUT) / (256 * 4), 256, 0, stream>>>(
      out, p1, sgate, b2, out);
}